// Round 8
// baseline (65.077 us; speedup 1.0000x reference)
//
#include <hip/hip_runtime.h>
#include <hip/hip_bf16.h>
#include <math.h>

// ImplicitPolygonInjector: B=4, C=128, H=W=64, S=4
// out[b][j][h*4+sy][w*4+sx] = (relu(hf[b,h,w,:]+hg[sy,sx,:]+b1) @ w2 + b2)[j] * gate[b,h,w]
//
// R7: barrier-free steady state. Each wave owns 16 m-rows x ALL 128 j:
// afrag = full w2^T in 128 VGPRs; B-fragments (hidden) built in registers from
// read-only LDS (hf bf16, hgb fp32) -- no hid buffer, no inter-wave dependency,
// NO barriers after the prologue. Stores throttle naturally at HBM rate.
// Block = (b,h,16w), grid 1024, 4 waves, ~24KB LDS, launch_bounds(256,2).

typedef __attribute__((ext_vector_type(8))) short bf16x8;
typedef __attribute__((ext_vector_type(4))) float f32x4;

__device__ inline short f2bf(float v) {
    __hip_bfloat16 b = __float2bfloat16(v);
    return *reinterpret_cast<short*>(&b);
}
__device__ inline float bf2f(short s) {
    __hip_bfloat16 b = *reinterpret_cast<__hip_bfloat16*>(&s);
    return __bfloat162float(b);
}

__device__ inline void barrier_lgkm() {
    asm volatile("s_waitcnt lgkmcnt(0)" ::: "memory");
    __builtin_amdgcn_s_barrier();
    asm volatile("" ::: "memory");
}

// ---------------- pre-kernel: transposes + bf16 hi/lo split ----------------
__global__ __launch_bounds__(256) void ipi_pre_kernel(
    const float* __restrict__ w2,    // (128,128)
    const float* __restrict__ w1,    // (130,128) -- rows 0..127 used
    const float* __restrict__ gw1,   // (128,32)
    __hip_bfloat16* __restrict__ w2t,     // (128j,128k)
    __hip_bfloat16* __restrict__ w1t_hi,  // (128j,128c)
    __hip_bfloat16* __restrict__ w1t_lo,
    __hip_bfloat16* __restrict__ g1t_hi,  // (32jg,128c)
    __hip_bfloat16* __restrict__ g1t_lo)
{
    int gid = blockIdx.x * 256 + threadIdx.x;
    if (gid < 16384) {
        int j = gid >> 7, k = gid & 127;
        w2t[gid] = __float2bfloat16(w2[k * 128 + j]);
    } else if (gid < 32768) {
        int i = gid - 16384, j = i >> 7, c = i & 127;
        float v = w1[c * 128 + j];
        __hip_bfloat16 hi = __float2bfloat16(v);
        w1t_hi[i] = hi;
        w1t_lo[i] = __float2bfloat16(v - __bfloat162float(hi));
    } else if (gid < 36864) {
        int i = gid - 32768, jg = i >> 7, c = i & 127;
        float v = gw1[c * 32 + jg];
        __hip_bfloat16 hi = __float2bfloat16(v);
        g1t_hi[i] = hi;
        g1t_lo[i] = __float2bfloat16(v - __bfloat162float(hi));
    }
}

// ---------------- main kernel ----------------
__global__ __launch_bounds__(256, 2) void ipi_main(
    const float* __restrict__ feat,     // (4,128,64,64)
    const float* __restrict__ mlp_w1,   // (130,128) -- rows 128,129 (grid coords)
    const float* __restrict__ mlp_b1,   // (128,)
    const float* __restrict__ gate_w2,  // (32,)
    const float* __restrict__ gate_b2,  // (1,)
    const float* __restrict__ mlp_b2,   // (128,)
    const __hip_bfloat16* __restrict__ w2t,
    const __hip_bfloat16* __restrict__ w1t_hi,
    const __hip_bfloat16* __restrict__ w1t_lo,
    const __hip_bfloat16* __restrict__ g1t_hi,
    const __hip_bfloat16* __restrict__ g1t_lo,
    float* __restrict__ out)            // (4,128,256,256)
{
    __shared__ short f_hi_s[16 * 136];  // [16 w][136 c] bf16 (prologue only)
    __shared__ short f_lo_s[16 * 136];
    __shared__ short hf_s[16 * 144];    // hf[w][k] bf16, stride 144 (bank-spread)
    __shared__ float hgb_s[16 * 132];   // hgb[s][k] fp32
    __shared__ float glds[16 * 33];     // gate hidden
    __shared__ float gate_s[16];

    const int t    = threadIdx.x;
    const int lane = t & 63;
    const int lg   = lane >> 4;         // 0..3 (k-group)
    const int ml   = lane & 15;
    const int wv   = t >> 6;            // wave id -> m-rows wv*16..+15
    const int bx   = blockIdx.x;
    const int w0   = (bx & 3) * 16;
    const int h    = (bx >> 2) & 63;
    const int b    = bx >> 8;

    // ---- stage f (transposed, bf16 hi/lo) + hgb ----
    {
        const float* fbase = feat + ((size_t)(b * 128) * 64 + h) * 64 + w0;
        #pragma unroll
        for (int i = 0; i < 8; ++i) {
            int idx = t + i * 256;            // 2048 = 128c * 16w
            int c = idx >> 4, w = idx & 15;
            float v = fbase[(size_t)c * 4096 + w];
            short hi = f2bf(v);
            f_hi_s[w * 136 + c] = hi;
            f_lo_s[w * 136 + c] = f2bf(v - bf2f(hi));
        }
        #pragma unroll
        for (int i = 0; i < 8; ++i) {
            int idx = t + i * 256;            // 2048 = 16s * 128k
            int s = idx >> 7, k = idx & 127;
            float cx = -0.75f + 0.5f * (float)(s & 3);
            float cy = -0.75f + 0.5f * (float)(s >> 2);
            hgb_s[s * 132 + k] = cx * mlp_w1[16384 + k]
                               + cy * mlp_w1[16512 + k] + mlp_b1[k];
        }
    }
    barrier_lgkm();

    // ---- hf = f @ w1_f via split-bf16 MFMA (all waves); gate MFMA (wave 0) ----
    {
        bf16x8 fhi[4], flo[4];
        {
            const short* fb  = f_hi_s + ml * 136 + lg * 8;
            const short* flb = f_lo_s + ml * 136 + lg * 8;
            #pragma unroll
            for (int ks = 0; ks < 4; ++ks) {
                fhi[ks] = *(const bf16x8*)(fb + ks * 32);
                flo[ks] = *(const bf16x8*)(flb + ks * 32);
            }
        }
        #pragma unroll
        for (int jj = 0; jj < 2; ++jj) {
            const int jt16 = (wv * 2 + jj) * 16;
            const __hip_bfloat16* bh = w1t_hi + (jt16 + ml) * 128 + lg * 8;
            const __hip_bfloat16* bl = w1t_lo + (jt16 + ml) * 128 + lg * 8;
            f32x4 acc = {0.f, 0.f, 0.f, 0.f};
            #pragma unroll
            for (int ks = 0; ks < 4; ++ks) {
                bf16x8 Bh = *(const bf16x8*)(bh + ks * 32);
                bf16x8 Bl = *(const bf16x8*)(bl + ks * 32);
                acc = __builtin_amdgcn_mfma_f32_16x16x32_bf16(fhi[ks], Bh, acc, 0, 0, 0);
                acc = __builtin_amdgcn_mfma_f32_16x16x32_bf16(fhi[ks], Bl, acc, 0, 0, 0);
                acc = __builtin_amdgcn_mfma_f32_16x16x32_bf16(flo[ks], Bh, acc, 0, 0, 0);
            }
            #pragma unroll
            for (int r = 0; r < 4; ++r)
                hf_s[(lg * 4 + r) * 144 + jt16 + ml] = f2bf(acc[r]);
        }
        if (wv == 0) {
            #pragma unroll
            for (int jt = 0; jt < 2; ++jt) {
                const __hip_bfloat16* bh = g1t_hi + (jt * 16 + ml) * 128 + lg * 8;
                const __hip_bfloat16* bl = g1t_lo + (jt * 16 + ml) * 128 + lg * 8;
                f32x4 acc = {0.f, 0.f, 0.f, 0.f};
                #pragma unroll
                for (int ks = 0; ks < 4; ++ks) {
                    bf16x8 Bh = *(const bf16x8*)(bh + ks * 32);
                    bf16x8 Bl = *(const bf16x8*)(bl + ks * 32);
                    acc = __builtin_amdgcn_mfma_f32_16x16x32_bf16(fhi[ks], Bh, acc, 0, 0, 0);
                    acc = __builtin_amdgcn_mfma_f32_16x16x32_bf16(fhi[ks], Bl, acc, 0, 0, 0);
                    acc = __builtin_amdgcn_mfma_f32_16x16x32_bf16(flo[ks], Bh, acc, 0, 0, 0);
                }
                #pragma unroll
                for (int r = 0; r < 4; ++r) {
                    float v = acc[r];
                    glds[(lg * 4 + r) * 33 + jt * 16 + ml] = (v >= 0.f) ? v : 0.2f * v;
                }
            }
        }
    }
    barrier_lgkm();

    // ---- gate = sigmoid(g @ gate_w2 + b2) ----
    if (t < 16) {
        float s = gate_b2[0];
        #pragma unroll 8
        for (int jg = 0; jg < 32; ++jg) s = fmaf(glds[t * 33 + jg], gate_w2[jg], s);
        gate_s[t] = 1.f / (1.f + expf(-s));
    }
    barrier_lgkm();   // LAST barrier; everything below reads read-only LDS

    // ---- per-thread persistent state ----
    const int mloc = wv * 16 + ml;      // m-row owned by this lane (0..63 in quarter)
    const int w    = mloc >> 2;         // 0..15
    const int sx   = mloc & 3;
    const float g  = gate_s[w];

    bf16x8 hfp[4];                      // hf[w][k], k = lg*8 + ks*32 .. +7
    #pragma unroll
    for (int ks = 0; ks < 4; ++ks)
        hfp[ks] = *(const bf16x8*)&hf_s[w * 144 + lg * 8 + ks * 32];

    bf16x8 afrag[8][4];                 // full w2^T: j-tile jt, rows jt*16+ml
    #pragma unroll
    for (int jt = 0; jt < 8; ++jt) {
        const __hip_bfloat16* base = w2t + (jt * 16 + ml) * 128 + lg * 8;
        #pragma unroll
        for (int ks = 0; ks < 4; ++ks)
            afrag[jt][ks] = *(const bf16x8*)(base + ks * 32);
    }
    f32x4 b2v[8];
    #pragma unroll
    for (int jt = 0; jt < 8; ++jt)
        b2v[jt] = *(const f32x4*)&mlp_b2[jt * 16 + lg * 4];

    float* pb = out + ((size_t)(b * 128 + lg * 4) << 16)
                    + (size_t)(h * 4) * 256 + w0 * 4 + mloc;

    // ---- steady state: 4 quarters (sy = q), ZERO barriers ----
    #pragma unroll 1
    for (int q = 0; q < 4; ++q) {
        f32x4 acc[8];
        #pragma unroll
        for (int jt = 0; jt < 8; ++jt) acc[jt] = b2v[jt];

        const float* hgr = hgb_s + (q * 4 + sx) * 132 + lg * 8;
        #pragma unroll
        for (int ks = 0; ks < 4; ++ks) {
            float4 ga = *(const float4*)(hgr + ks * 32);
            float4 gb = *(const float4*)(hgr + ks * 32 + 4);
            bf16x8 bf;
            bf[0] = f2bf(fmaxf(bf2f(hfp[ks][0]) + ga.x, 0.f));
            bf[1] = f2bf(fmaxf(bf2f(hfp[ks][1]) + ga.y, 0.f));
            bf[2] = f2bf(fmaxf(bf2f(hfp[ks][2]) + ga.z, 0.f));
            bf[3] = f2bf(fmaxf(bf2f(hfp[ks][3]) + ga.w, 0.f));
            bf[4] = f2bf(fmaxf(bf2f(hfp[ks][4]) + gb.x, 0.f));
            bf[5] = f2bf(fmaxf(bf2f(hfp[ks][5]) + gb.y, 0.f));
            bf[6] = f2bf(fmaxf(bf2f(hfp[ks][6]) + gb.z, 0.f));
            bf[7] = f2bf(fmaxf(bf2f(hfp[ks][7]) + gb.w, 0.f));
            #pragma unroll
            for (int jt = 0; jt < 8; ++jt)
                acc[jt] = __builtin_amdgcn_mfma_f32_16x16x32_bf16(afrag[jt][ks], bf, acc[jt], 0, 0, 0);
        }

        float* op = pb + q * 256;
        #pragma unroll
        for (int jt = 0; jt < 8; ++jt) {
            #pragma unroll
            for (int r = 0; r < 4; ++r)
                op[(size_t)(jt * 16 + r) << 16] = acc[jt][r] * g;
        }
    }
}

extern "C" void kernel_launch(void* const* d_in, const int* in_sizes, int n_in,
                              void* d_out, int out_size, void* d_ws, size_t ws_size,
                              hipStream_t stream) {
    const float* feat = (const float*)d_in[0];
    const float* gw1  = (const float*)d_in[1];
    const float* gw2  = (const float*)d_in[2];
    const float* gb2  = (const float*)d_in[3];
    const float* w1   = (const float*)d_in[4];
    const float* b1   = (const float*)d_in[5];
    const float* w2   = (const float*)d_in[6];
    const float* b2   = (const float*)d_in[7];
    float* o = (float*)d_out;

    // ws: w2t 32K | w1t_hi 32K | w1t_lo 32K | g1t_hi 8K | g1t_lo 8K = 112K
    char* ws = (char*)d_ws;
    __hip_bfloat16* w2t    = (__hip_bfloat16*)(ws);
    __hip_bfloat16* w1t_hi = (__hip_bfloat16*)(ws + 32768);
    __hip_bfloat16* w1t_lo = (__hip_bfloat16*)(ws + 65536);
    __hip_bfloat16* g1t_hi = (__hip_bfloat16*)(ws + 98304);
    __hip_bfloat16* g1t_lo = (__hip_bfloat16*)(ws + 106496);

    ipi_pre_kernel<<<dim3(144), dim3(256), 0, stream>>>(
        w2, w1, gw1, w2t, w1t_hi, w1t_lo, g1t_hi, g1t_lo);
    ipi_main<<<dim3(1024), dim3(256), 0, stream>>>(
        feat, w1, b1, gw2, gb2, b2, w2t, w1t_hi, w1t_lo, g1t_hi, g1t_lo, o);
}

// Round 9
// 44.968 us; speedup vs baseline: 1.4472x; 1.4472x over previous
//
#include <hip/hip_runtime.h>
#include <hip/hip_bf16.h>
#include <math.h>

// ImplicitPolygonInjector: B=4, C=128, H=W=64, S=4
// out[b][j][h*4+sy][w*4+sx] = (relu(hf[b,h,w,:]+hg[sy,sx,:]+b1) @ w2 + b2)[j] * gate[b,h,w]
//
// R8 = R3 (best measured, 44.4us) with ONE change: MFMA operand flip in phase B.
// D[m][j] = mfma(hidden_frag(A), w2T_frag(B), b2) -> each lane holds 4 consecutive
// x for one j-plane -> float4 stores (8/quarter/wave instead of 32 scalar), 1KB per
// wave-store-instr, compile-time store offsets. Phase A / prologue / barriers
// identical to R3. lgkm-only barriers; no global loads in steady state.

typedef __attribute__((ext_vector_type(8))) short bf16x8;
typedef __attribute__((ext_vector_type(4))) float f32x4;

__device__ inline short f2bf(float v) {
    __hip_bfloat16 b = __float2bfloat16(v);
    return *reinterpret_cast<short*>(&b);
}

__device__ inline void barrier_lgkm() {
    asm volatile("s_waitcnt lgkmcnt(0)" ::: "memory");
    __builtin_amdgcn_s_barrier();
    asm volatile("" ::: "memory");
}

// ---------------- pre-kernel: transposes + bf16 hi/lo split ----------------
__global__ __launch_bounds__(256) void ipi_pre_kernel(
    const float* __restrict__ w2,    // (128,128)
    const float* __restrict__ w1,    // (130,128) -- rows 0..127 used
    const float* __restrict__ gw1,   // (128,32)
    __hip_bfloat16* __restrict__ w2t,     // (128j,128k)
    __hip_bfloat16* __restrict__ w1t_hi,  // (128j,128c)
    __hip_bfloat16* __restrict__ w1t_lo,
    __hip_bfloat16* __restrict__ g1t_hi,  // (32jg,128c)
    __hip_bfloat16* __restrict__ g1t_lo)
{
    int gid = blockIdx.x * 256 + threadIdx.x;
    if (gid < 16384) {
        int j = gid >> 7, k = gid & 127;
        w2t[gid] = __float2bfloat16(w2[k * 128 + j]);
    } else if (gid < 32768) {
        int i = gid - 16384, j = i >> 7, c = i & 127;
        float v = w1[c * 128 + j];
        __hip_bfloat16 hi = __float2bfloat16(v);
        w1t_hi[i] = hi;
        w1t_lo[i] = __float2bfloat16(v - __bfloat162float(hi));
    } else if (gid < 36864) {
        int i = gid - 32768, jg = i >> 7, c = i & 127;
        float v = gw1[c * 32 + jg];
        __hip_bfloat16 hi = __float2bfloat16(v);
        g1t_hi[i] = hi;
        g1t_lo[i] = __float2bfloat16(v - __bfloat162float(hi));
    }
}

// ---------------- main kernel ----------------
__global__ __launch_bounds__(256, 4) void ipi_main(
    const float* __restrict__ feat,     // (4,128,64,64)
    const float* __restrict__ mlp_w1,   // (130,128) -- rows 128,129 (grid coords)
    const float* __restrict__ mlp_b1,   // (128,)
    const float* __restrict__ gate_w2,  // (32,)
    const float* __restrict__ gate_b2,  // (1,)
    const float* __restrict__ mlp_b2,   // (128,)
    const __hip_bfloat16* __restrict__ w2t,
    const __hip_bfloat16* __restrict__ w1t_hi,
    const __hip_bfloat16* __restrict__ w1t_lo,
    const __hip_bfloat16* __restrict__ g1t_hi,
    const __hip_bfloat16* __restrict__ g1t_lo,
    float* __restrict__ out)            // (4,128,256,256)
{
    __shared__ float hf_s[16 * 132];    // hf[w][k] fp32
    __shared__ float hgb_s[16 * 132];   // hgb[s][k] fp32
    __shared__ float gate_s[16];
    __shared__ char  hid[16384];        // 2 x 8KB: bf16 [32 m][128 k] swizzled
    short* f_hi = (short*)hid;          // [16 w][136 c]  (prologue only)
    short* f_lo = (short*)(hid + 4352);
    float* glds = (float*)(hid + 8704); // [16 w][33 jg]  (dead after sigmoid)

    const int t    = threadIdx.x;
    const int lane = t & 63;
    const int lg   = lane >> 4;         // 0..3
    const int ml   = lane & 15;
    const int wv   = t >> 6;            // wave id -> j-range wv*32..+31
    const int bx   = blockIdx.x;
    const int w0   = (bx & 3) * 16;
    const int h    = (bx >> 2) & 63;
    const int b    = bx >> 8;

    // ---- w2t fragments (B-operand role now: col j = ml, k = lg*8+ks*32) + b2 ----
    bf16x8 wfrag[2][4];
    f32x4  b2s[2];
    {
        const __hip_bfloat16* base = w2t + (wv * 32 + ml) * 128 + lg * 8;
        #pragma unroll
        for (int jt = 0; jt < 2; ++jt) {
            #pragma unroll
            for (int ks = 0; ks < 4; ++ks)
                wfrag[jt][ks] = *(const bf16x8*)(base + jt * 2048 + ks * 32);
            float bj = mlp_b2[wv * 32 + jt * 16 + ml];
            b2s[jt] = (f32x4){bj, bj, bj, bj};
        }
    }

    // store base: plane j = wv*32 + jt*16 + ml; x = w0*4 + mt*16 + lg*4 (+r)
    float* pq = out + ((size_t)(b * 128 + wv * 32 + ml) << 16)
                    + (size_t)(h * 4) * 256 + w0 * 4 + lg * 4;

    // ---- stage f (transposed, bf16 hi/lo) + hgb ----
    {
        const float* fbase = feat + ((size_t)(b * 128) * 64 + h) * 64 + w0;
        #pragma unroll
        for (int i = 0; i < 8; ++i) {
            int idx = t + i * 256;            // 2048 = 128c * 16w
            int c = idx >> 4, w = idx & 15;
            float v = fbase[(size_t)c * 4096 + w];
            short hi = f2bf(v);
            float hf32 = __bfloat162float(*(__hip_bfloat16*)&hi);
            f_hi[w * 136 + c] = hi;
            f_lo[w * 136 + c] = f2bf(v - hf32);
        }
        #pragma unroll
        for (int i = 0; i < 8; ++i) {
            int idx = t + i * 256;            // 2048 = 16s * 128k
            int s = idx >> 7, k = idx & 127;
            float cx = -0.75f + 0.5f * (float)(s & 3);
            float cy = -0.75f + 0.5f * (float)(s >> 2);
            hgb_s[s * 132 + k] = cx * mlp_w1[16384 + k]
                               + cy * mlp_w1[16512 + k] + mlp_b1[k];
        }
    }
    barrier_lgkm();

    // ---- hf = f @ w1_f via split-bf16 MFMA (all waves); gate MFMA (wave 0) ----
    {
        bf16x8 fhi[4], flo[4];
        {
            const short* fb  = f_hi + ml * 136 + lg * 8;
            const short* flb = f_lo + ml * 136 + lg * 8;
            #pragma unroll
            for (int ks = 0; ks < 4; ++ks) {
                fhi[ks] = *(const bf16x8*)(fb + ks * 32);
                flo[ks] = *(const bf16x8*)(flb + ks * 32);
            }
        }
        #pragma unroll
        for (int jj = 0; jj < 2; ++jj) {
            const int jt16 = (wv * 2 + jj) * 16;
            const __hip_bfloat16* bh = w1t_hi + (jt16 + ml) * 128 + lg * 8;
            const __hip_bfloat16* bl = w1t_lo + (jt16 + ml) * 128 + lg * 8;
            f32x4 acc = {0.f, 0.f, 0.f, 0.f};
            #pragma unroll
            for (int ks = 0; ks < 4; ++ks) {
                bf16x8 Bh = *(const bf16x8*)(bh + ks * 32);
                bf16x8 Bl = *(const bf16x8*)(bl + ks * 32);
                acc = __builtin_amdgcn_mfma_f32_16x16x32_bf16(fhi[ks], Bh, acc, 0, 0, 0);
                acc = __builtin_amdgcn_mfma_f32_16x16x32_bf16(fhi[ks], Bl, acc, 0, 0, 0);
                acc = __builtin_amdgcn_mfma_f32_16x16x32_bf16(flo[ks], Bh, acc, 0, 0, 0);
            }
            #pragma unroll
            for (int r = 0; r < 4; ++r)
                hf_s[(lg * 4 + r) * 132 + jt16 + ml] = acc[r];
        }
        if (wv == 0) {
            #pragma unroll
            for (int jt = 0; jt < 2; ++jt) {
                const __hip_bfloat16* bh = g1t_hi + (jt * 16 + ml) * 128 + lg * 8;
                const __hip_bfloat16* bl = g1t_lo + (jt * 16 + ml) * 128 + lg * 8;
                f32x4 acc = {0.f, 0.f, 0.f, 0.f};
                #pragma unroll
                for (int ks = 0; ks < 4; ++ks) {
                    bf16x8 Bh = *(const bf16x8*)(bh + ks * 32);
                    bf16x8 Bl = *(const bf16x8*)(bl + ks * 32);
                    acc = __builtin_amdgcn_mfma_f32_16x16x32_bf16(fhi[ks], Bh, acc, 0, 0, 0);
                    acc = __builtin_amdgcn_mfma_f32_16x16x32_bf16(fhi[ks], Bl, acc, 0, 0, 0);
                    acc = __builtin_amdgcn_mfma_f32_16x16x32_bf16(flo[ks], Bh, acc, 0, 0, 0);
                }
                #pragma unroll
                for (int r = 0; r < 4; ++r) {
                    float v = acc[r];
                    glds[(lg * 4 + r) * 33 + jt * 16 + ml] = (v >= 0.f) ? v : 0.2f * v;
                }
            }
        }
    }
    barrier_lgkm();

    // ---- gate = sigmoid(g @ gate_w2 + b2) ----
    if (t < 16) {
        float s = gate_b2[0];
        #pragma unroll 8
        for (int jg = 0; jg < 32; ++jg) s = fmaf(glds[t * 33 + jg], gate_w2[jg], s);
        gate_s[t] = 1.f / (1.f + expf(-s));
    }
    barrier_lgkm();

    // ---- steady state: 4 quarters (sy = q); {A; bar; B+float4 stores; bar} ----
    const int mq  = t >> 3;             // 0..31 (two chunk-halves per quarter below)
    const int kq  = t & 7;
    for (int q = 0; q < 4; ++q) {
        // phase A: hid[m][k] = bf16(relu(hf[w][k] + hgb[q*4+sx][k])), 64 m rows
        {
            const int m0 = t >> 2;                    // 0..63
            const int w  = m0 >> 2;
            const int s  = (q << 2) | (m0 & 3);
            const float* hfr = hf_s  + w * 132 + (t & 3) * 32;
            const float* hgr = hgb_s + s * 132 + (t & 3) * 32;
            char* wp = hid + (m0 & 31) * 256 + (m0 >> 5) * 8192;
            const int sw = (m0 & 7) << 4;
            const int kb = (t & 3) * 64;
            #pragma unroll
            for (int kc = 0; kc < 4; ++kc) {
                float4 a0 = *(const float4*)(hfr + kc * 8);
                float4 a1 = *(const float4*)(hfr + kc * 8 + 4);
                float4 g0 = *(const float4*)(hgr + kc * 8);
                float4 g1 = *(const float4*)(hgr + kc * 8 + 4);
                bf16x8 hv;
                hv[0] = f2bf(fmaxf(a0.x + g0.x, 0.f));
                hv[1] = f2bf(fmaxf(a0.y + g0.y, 0.f));
                hv[2] = f2bf(fmaxf(a0.z + g0.z, 0.f));
                hv[3] = f2bf(fmaxf(a0.w + g0.w, 0.f));
                hv[4] = f2bf(fmaxf(a1.x + g1.x, 0.f));
                hv[5] = f2bf(fmaxf(a1.y + g1.y, 0.f));
                hv[6] = f2bf(fmaxf(a1.z + g1.z, 0.f));
                hv[7] = f2bf(fmaxf(a1.w + g1.w, 0.f));
                *(bf16x8*)(wp + ((kb + kc * 16) ^ sw)) = hv;
            }
        }
        barrier_lgkm();

        // phase B: D[m][j] = mfma(hid_frag, w2t_frag, b2); float4 gated stores
        #pragma unroll
        for (int mt = 0; mt < 4; ++mt) {
            const int mrow = mt * 16 + ml;           // m row (A-operand row = ml)
            const int swb  = ((mrow & 7) << 4);
            const char* rp = hid + (mrow & 31) * 256 + (mrow >> 5) * 8192;
            bf16x8 hfrag[4];
            #pragma unroll
            for (int ks = 0; ks < 4; ++ks)
                hfrag[ks] = *(const bf16x8*)(rp + ((ks * 64 + lg * 16) ^ swb));

            const float g = gate_s[mt * 4 + lg];     // w = (mt*16+lg*4+r)>>2 = mt*4+lg

            #pragma unroll
            for (int jt = 0; jt < 2; ++jt) {
                f32x4 acc = b2s[jt];
                #pragma unroll
                for (int ks = 0; ks < 4; ++ks)
                    acc = __builtin_amdgcn_mfma_f32_16x16x32_bf16(hfrag[ks], wfrag[jt][ks], acc, 0, 0, 0);
                float4 o;
                o.x = acc[0] * g; o.y = acc[1] * g;
                o.z = acc[2] * g; o.w = acc[3] * g;
                *(float4*)(pq + ((size_t)(jt * 16) << 16) + q * 256 + mt * 16) = o;
            }
        }
        barrier_lgkm();
    }
    (void)mq; (void)kq;
}

extern "C" void kernel_launch(void* const* d_in, const int* in_sizes, int n_in,
                              void* d_out, int out_size, void* d_ws, size_t ws_size,
                              hipStream_t stream) {
    const float* feat = (const float*)d_in[0];
    const float* gw1  = (const float*)d_in[1];
    const float* gw2  = (const float*)d_in[2];
    const float* gb2  = (const float*)d_in[3];
    const float* w1   = (const float*)d_in[4];
    const float* b1   = (const float*)d_in[5];
    const float* w2   = (const float*)d_in[6];
    const float* b2   = (const float*)d_in[7];
    float* o = (float*)d_out;

    // ws: w2t 32K | w1t_hi 32K | w1t_lo 32K | g1t_hi 8K | g1t_lo 8K = 112K
    char* ws = (char*)d_ws;
    __hip_bfloat16* w2t    = (__hip_bfloat16*)(ws);
    __hip_bfloat16* w1t_hi = (__hip_bfloat16*)(ws + 32768);
    __hip_bfloat16* w1t_lo = (__hip_bfloat16*)(ws + 65536);
    __hip_bfloat16* g1t_hi = (__hip_bfloat16*)(ws + 98304);
    __hip_bfloat16* g1t_lo = (__hip_bfloat16*)(ws + 106496);

    ipi_pre_kernel<<<dim3(144), dim3(256), 0, stream>>>(
        w2, w1, gw1, w2t, w1t_hi, w1t_lo, g1t_hi, g1t_lo);
    ipi_main<<<dim3(1024), dim3(256), 0, stream>>>(
        feat, w1, b1, gw2, gb2, b2, w2t, w1t_hi, w1t_lo, g1t_hi, g1t_lo, o);
}